// Round 2
// baseline (155.705 us; speedup 1.0000x reference)
//
#include <hip/hip_runtime.h>
#include <math.h>

#define NG 1024
#define IMG_W 256
#define IMG_H 256
#define JITTER 1e-6f

// Per-gaussian precomputed params, padded to 32 B so the composite loop's
// wave-uniform access can be a single s_load_dwordx8.
struct GParam { float mx, my, A, B, D, op, pad0, pad1; };
__device__ GParam g_params[NG];

__global__ __launch_bounds__(256)
void gs_precompute(const float* __restrict__ means,
                   const float* __restrict__ scales,
                   const float* __restrict__ thetas,
                   const float* __restrict__ opacities) {
    int g = blockIdx.x * blockDim.x + threadIdx.x;
    if (g >= NG) return;

    float mx = tanhf(means[2 * g]);
    float my = tanhf(means[2 * g + 1]);

    // s^2 = exp(scales)^2 = exp(2*scales)
    float s2x = expf(2.0f * scales[2 * g]);
    float s2y = expf(2.0f * scales[2 * g + 1]);

    float th = (1.0f / (1.0f + expf(-thetas[g]))) * 6.2831853071795864769f;
    float si, c;
    sincosf(th, &si, &c);

    float a = c * c * s2x + si * si * s2y + JITTER;   // Sigma_00
    float b = c * si * (s2x - s2y);                   // Sigma_01
    float d = si * si * s2x + c * c * s2y + JITTER;   // Sigma_11
    float det = a * d - b * b;
    float inv_det = 1.0f / det;
    float ia = d * inv_det;
    float ib = -b * inv_det;
    float idd = a * inv_det;

    // alpha = op * exp(-0.5*q), q = ia*dx^2 + 2*ib*dx*dy + idd*dy^2
    // Fold -0.5*log2(e) so inner loop uses exp2 (native v_exp_f32):
    // e2 = A*dx^2 + B*dx*dy + D*dy^2 ; alpha = op * exp2(e2)
    const float L2E = 1.4426950408889634f;
    GParam p;
    p.mx = mx;
    p.my = my;
    p.A = -0.5f * L2E * ia;
    p.B = -L2E * ib;
    p.D = -0.5f * L2E * idd;
    p.op = 1.0f / (1.0f + expf(-opacities[g]));
    p.pad0 = 0.0f;
    p.pad1 = 0.0f;
    g_params[g] = p;
}

__global__ __launch_bounds__(256)
void gs_composite(float* __restrict__ out) {
    int p = blockIdx.x * 256 + threadIdx.x;   // pixel index
    int i = p >> 8;                            // row    (y)
    int j = p & 255;                           // column (x)

    const float step = 2.0f / 255.0f;          // linspace(-1,1,256)
    float x = fmaf((float)j, step, -1.0f);
    float y = fmaf((float)i, step, -1.0f);

    float acc = 0.0f;
    float T = 1.0f;

    const GParam* __restrict__ gp = g_params;
    #pragma unroll 4
    for (int g = 0; g < NG; ++g) {
        GParam q = gp[g];
        float dx = x - q.mx;
        float dy = y - q.my;
        // e2 = A*dx^2 + B*dx*dy + D*dy^2
        float e2 = fmaf(dx, fmaf(q.A, dx, q.B * dy), q.D * (dy * dy));
        float alpha = q.op * __builtin_amdgcn_exp2f(e2);
        acc = fmaf(alpha, T, acc);
        T = fmaf(-alpha, T, T);
    }

    // bg = (0,0,0): image[...,c] = acc for all 3 channels
    float* o = out + 3 * p;
    o[0] = acc;
    o[1] = acc;
    o[2] = acc;
}

extern "C" void kernel_launch(void* const* d_in, const int* in_sizes, int n_in,
                              void* d_out, int out_size, void* d_ws, size_t ws_size,
                              hipStream_t stream) {
    const float* means     = (const float*)d_in[0];
    const float* scales    = (const float*)d_in[1];
    const float* thetas    = (const float*)d_in[2];
    const float* opacities = (const float*)d_in[3];
    float* out = (float*)d_out;

    gs_precompute<<<dim3(NG / 256), dim3(256), 0, stream>>>(means, scales, thetas, opacities);
    gs_composite<<<dim3((IMG_W * IMG_H) / 256), dim3(256), 0, stream>>>(out);
}

// Round 3
// 80.686 us; speedup vs baseline: 1.9298x; 1.9298x over previous
//
#include <hip/hip_runtime.h>
#include <math.h>

#define NG 1024
#define NSEG 8
#define SEG_LEN (NG / NSEG)   // 128 gaussians per segment (one wave each)
#define IMG_W 256
#define IMG_H 256
#define JITTER 1e-6f
#define L2E 1.4426950408889634f

// Per-gaussian precomputed params, padded to 32 B so the composite loop's
// wave-uniform access is a single s_load_dwordx8.
struct GParam { float mx, my, A, B, D, op, pad0, pad1; };
__device__ GParam g_params[NG];

__device__ __forceinline__ float fexp2(float x)  { return __builtin_amdgcn_exp2f(x); }
__device__ __forceinline__ float frcp(float x)   { return __builtin_amdgcn_rcpf(x); }
__device__ __forceinline__ float fexp(float x)   { return fexp2(x * L2E); }
__device__ __forceinline__ float fsigmoid(float x) { return frcp(1.0f + fexp(-x)); }
__device__ __forceinline__ float ftanh(float x) {
    // tanh(x) = 1 - 2/(exp(2x)+1)
    float t = fexp2(2.0f * L2E * x);
    return 1.0f - 2.0f * frcp(t + 1.0f);
}

__global__ __launch_bounds__(256)
void gs_precompute(const float* __restrict__ means,
                   const float* __restrict__ scales,
                   const float* __restrict__ thetas,
                   const float* __restrict__ opacities) {
    int g = blockIdx.x * blockDim.x + threadIdx.x;
    if (g >= NG) return;

    float mx = ftanh(means[2 * g]);
    float my = ftanh(means[2 * g + 1]);

    // s^2 = exp(scales)^2 = exp(2*scales)
    float s2x = fexp(2.0f * scales[2 * g]);
    float s2y = fexp(2.0f * scales[2 * g + 1]);

    // theta = sigmoid(t)*2pi. v_sin/cos_f32 take input in REVOLUTIONS, and
    // theta/2pi = sigmoid(t) in (0,1) -> feed sigmoid directly, no reduction.
    float rev = fsigmoid(thetas[g]);
    float si = __builtin_amdgcn_sinf(rev);
    float c  = __builtin_amdgcn_cosf(rev);

    float a = c * c * s2x + si * si * s2y + JITTER;   // Sigma_00
    float b = c * si * (s2x - s2y);                   // Sigma_01
    float d = si * si * s2x + c * c * s2y + JITTER;   // Sigma_11
    float det = a * d - b * b;
    float inv_det = frcp(det);
    float ia = d * inv_det;
    float ib = -b * inv_det;
    float idd = a * inv_det;

    // alpha = op*exp(-0.5*q), q = ia*dx^2 + 2*ib*dx*dy + idd*dy^2
    // Fold -0.5*log2(e) so the inner loop uses native exp2:
    // alpha = op * exp2(A*dx^2 + B*dx*dy + D*dy^2)
    GParam p;
    p.mx = mx;
    p.my = my;
    p.A = -0.5f * L2E * ia;
    p.B = -L2E * ib;
    p.D = -0.5f * L2E * idd;
    p.op = fsigmoid(opacities[g]);
    p.pad0 = 0.0f;
    p.pad1 = 0.0f;
    g_params[g] = p;
}

// Block = 512 threads = 8 waves. Wave w handles gaussian segment
// [w*128, (w+1)*128) for the block's 64 pixels (lane = pixel). Segment
// results (acc, T) combine in order via LDS: (A,T)o(a,t) = (A+T*a, T*t).
__global__ __launch_bounds__(512, 8)
void gs_composite(float* __restrict__ out) {
    __shared__ float2 seg_res[NSEG * 64];

    int tid  = threadIdx.x;
    int lane = tid & 63;
    // Force segment index into an SGPR so param loads stay s_load_dwordx8.
    int seg = __builtin_amdgcn_readfirstlane(tid >> 6);

    int p = blockIdx.x * 64 + lane;            // pixel index
    int i = p >> 8;                            // row    (y) — block-uniform
    int j = p & 255;                           // column (x)

    const float step = 2.0f / 255.0f;          // linspace(-1,1,256)
    float x = fmaf((float)j, step, -1.0f);
    float y = fmaf((float)i, step, -1.0f);

    float acc = 0.0f;
    float T = 1.0f;

    const GParam* __restrict__ gp = g_params + seg * SEG_LEN;
    #pragma unroll 4
    for (int g = 0; g < SEG_LEN; ++g) {
        GParam q = gp[g];
        float dx = x - q.mx;
        float dy = y - q.my;
        float e2 = fmaf(dx, fmaf(q.A, dx, q.B * dy), q.D * (dy * dy));
        float alpha = q.op * fexp2(e2);
        acc = fmaf(alpha, T, acc);
        T = fmaf(-alpha, T, T);
    }

    seg_res[seg * 64 + lane] = make_float2(acc, T);
    __syncthreads();

    if (tid < 64) {
        // wave 0's registers already hold segment 0's result
        float A = acc, Tt = T;
        #pragma unroll
        for (int s = 1; s < NSEG; ++s) {
            float2 v = seg_res[s * 64 + lane];
            A = fmaf(Tt, v.x, A);
            Tt *= v.y;
        }
        // bg = (0,0,0): image[...,c] = A for all 3 channels
        float* o = out + 3 * p;
        o[0] = A;
        o[1] = A;
        o[2] = A;
    }
}

extern "C" void kernel_launch(void* const* d_in, const int* in_sizes, int n_in,
                              void* d_out, int out_size, void* d_ws, size_t ws_size,
                              hipStream_t stream) {
    const float* means     = (const float*)d_in[0];
    const float* scales    = (const float*)d_in[1];
    const float* thetas    = (const float*)d_in[2];
    const float* opacities = (const float*)d_in[3];
    float* out = (float*)d_out;

    gs_precompute<<<dim3(NG / 256), dim3(256), 0, stream>>>(means, scales, thetas, opacities);
    gs_composite<<<dim3((IMG_W * IMG_H) / 64), dim3(512), 0, stream>>>(out);
}